// Round 1
// baseline (129.153 us; speedup 1.0000x reference)
//
#include <hip/hip_runtime.h>

#define T_SEQ 2048
#define C_EMB 1024
#define C_QKV 1536
#define N_HEAD 16

typedef __bf16 bf16x8 __attribute__((ext_vector_type(8)));
typedef __bf16 bf16x4 __attribute__((ext_vector_type(4)));
typedef float  f32x4  __attribute__((ext_vector_type(4)));

// async 16B global -> LDS (global_load_lds_dwordx4).
// HW contract: LDS dest = wave-uniform base + lane*16B.
__device__ __forceinline__ void load_lds16(const __bf16* g, __bf16* l)
{
    __builtin_amdgcn_global_load_lds(
        (const __attribute__((address_space(1))) unsigned int*)g,
        (__attribute__((address_space(3))) unsigned int*)l, 16, 0, 0);
}

// ---------------------------------------------------------------------------
// Fused prep (r12 winner): blocks [0,384) transpose-convert w_attn,
// [384,640) w_proj, [640,896) grid-stride convert x.
// ---------------------------------------------------------------------------
__device__ __forceinline__ void tconv_tile(
    const float* __restrict__ in, __bf16* __restrict__ out,
    int R, int C, int r0, int c0, float (*lds)[65], int t)
{
#pragma unroll
    for (int k = 0; k < 16; k++) {
        int r = k * 4 + (t >> 6), c = t & 63;
        lds[r][c] = in[(size_t)(r0 + r) * C + c0 + c];
    }
    __syncthreads();
#pragma unroll
    for (int k = 0; k < 16; k++) {
        int cc = k * 4 + (t >> 6), rr = t & 63;
        out[(size_t)(c0 + cc) * R + r0 + rr] = (__bf16)lds[rr][cc];
    }
}

__global__ __launch_bounds__(256) void prep_kernel(
    const float* __restrict__ x, const float* __restrict__ wa,
    const float* __restrict__ wp, __bf16* __restrict__ x_bf,
    __bf16* __restrict__ waT, __bf16* __restrict__ wpT)
{
    __shared__ float lds[64][65];
    const int b = blockIdx.x, t = threadIdx.x;
    if (b < 384) {                      // w_attn [1024][1536] -> waT [1536][1024]
        tconv_tile(wa, waT, C_EMB, C_QKV, (b / 24) * 64, (b % 24) * 64, lds, t);
    } else if (b < 640) {               // w_proj [1024][1024] -> wpT [1024][1024]
        int b2 = b - 384;
        tconv_tile(wp, wpT, C_EMB, C_EMB, (b2 / 16) * 64, (b2 % 16) * 64, lds, t);
    } else {                            // x fp32 -> bf16
        for (int gi = (b - 640) * 256 + t; gi < T_SEQ * C_EMB / 8; gi += 65536) {
            float4 v0 = ((const float4*)x)[gi * 2];
            float4 v1 = ((const float4*)x)[gi * 2 + 1];
            bf16x8 o = { (__bf16)v0.x, (__bf16)v0.y, (__bf16)v0.z, (__bf16)v0.w,
                         (__bf16)v1.x, (__bf16)v1.y, (__bf16)v1.z, (__bf16)v1.w };
            ((bf16x8*)x_bf)[gi] = o;
        }
    }
}

// ---------------------------------------------------------------------------
// bf16 MFMA GEMM (r12 winner, unchanged): C = A(MxK) @ Bt(NxK)^T.
// 64x64 tile, BK=64, 4 waves (2x2), wave 32x32. GEMM1: 768 blocks = 3/CU,
// GEMM2: 512 = 2/CU. XOR-swizzled unpadded LDS + global_load_lds + dbuf.
// FUSE_QKV epilogue: RoPE (partner col via __shfl_xor(.,1)), q cols
// pre-scaled by 0.125*log2e, v cols scattered into Vt[g*64+d][t].
// ---------------------------------------------------------------------------
template <bool FUSE_QKV>
__global__ __launch_bounds__(256) void gemm_mfma_kernel(
    const __bf16* __restrict__ A, const __bf16* __restrict__ Bt,
    __bf16* __restrict__ Cq, __bf16* __restrict__ Vt,
    float* __restrict__ Cf, int M, int N, int K)
{
    __shared__ __align__(16) __bf16 As0[64 * 64], As1[64 * 64];
    __shared__ __align__(16) __bf16 Bs0[64 * 64], Bs1[64 * 64];

    const int tid = threadIdx.x;
    const int l = tid & 63, w = tid >> 6;
    const int ln = l & 15, q = l >> 4;
    const int wm = (w & 1) * 32, wn = (w >> 1) * 32;
    const int row0 = blockIdx.y * 64, col0 = blockIdx.x * 64;

    f32x4 acc[2][2];
#pragma unroll
    for (int mi = 0; mi < 2; mi++)
#pragma unroll
        for (int ni = 0; ni < 2; ni++) acc[mi][ni] = (f32x4){0.f, 0.f, 0.f, 0.f};

    auto stage = [&](int k0, __bf16* as, __bf16* bs) {
#pragma unroll
        for (int p = 0; p < 2; p++) {
            int r = p * 32 + w * 8 + (l >> 3);
            int cc = (l & 7) ^ (r & 7);           // swizzled source chunk
            load_lds16(A + (size_t)(row0 + r) * K + k0 + cc * 8,
                       as + p * 2048 + w * 512);  // wave-uniform base
            load_lds16(Bt + (size_t)(col0 + r) * K + k0 + cc * 8,
                       bs + p * 2048 + w * 512);
        }
    };
    auto compute = [&](const __bf16* as, const __bf16* bs) {
#pragma unroll
        for (int ki = 0; ki < 2; ki++) {
            bf16x8 af[2], bfr[2];
#pragma unroll
            for (int mi = 0; mi < 2; mi++)
                af[mi] = *(const bf16x8*)&as[(wm + mi * 16 + ln) * 64 +
                                             (((ki * 4 + q) ^ (ln & 7)) * 8)];
#pragma unroll
            for (int ni = 0; ni < 2; ni++)
                bfr[ni] = *(const bf16x8*)&bs[(wn + ni * 16 + ln) * 64 +
                                              (((ki * 4 + q) ^ (ln & 7)) * 8)];
#pragma unroll
            for (int mi = 0; mi < 2; mi++)
#pragma unroll
                for (int ni = 0; ni < 2; ni++)
                    acc[mi][ni] = __builtin_amdgcn_mfma_f32_16x16x32_bf16(
                        af[mi], bfr[ni], acc[mi][ni], 0, 0, 0);
        }
    };

    stage(0, As0, Bs0);
    for (int k0 = 0;; k0 += 128) {
        __syncthreads();                      // buf0 fill drained
        if (k0 + 64 < K) stage(k0 + 64, As1, Bs1);
        compute(As0, Bs0);
        if (k0 + 64 >= K) break;
        __syncthreads();                      // buf1 fill drained
        if (k0 + 128 < K) stage(k0 + 128, As0, Bs0);
        compute(As1, Bs1);
        if (k0 + 128 >= K) break;
    }

    // C/D layout: col = lane&15, row = quad*4 + reg
#pragma unroll
    for (int mi = 0; mi < 2; mi++)
#pragma unroll
        for (int ni = 0; ni < 2; ni++) {
            const int col = col0 + wn + ni * 16 + ln;
            if (!FUSE_QKV) {
#pragma unroll
                for (int reg = 0; reg < 4; reg++) {
                    int row = row0 + wm + mi * 16 + 4 * q + reg;
                    Cf[(size_t)row * N + col] = acc[mi][ni][reg];
                }
            } else {
                // per-group col layout (384): q [0,256), k [256,320), v [320,384)
                const int r = col % 384;
                const int gg = col / 384;
                if (r < 320) {
                    const int d = r & 63;
                    const float inv_freq =
                        __expf(-(float)(d & ~1) * (9.210340371976184f / 64.0f));
                    const float sgn = (d & 1) ? 1.0f : -1.0f;
                    const float osc = (r < 256) ? 0.18033688011112042f : 1.0f;
#pragma unroll
                    for (int reg = 0; reg < 4; reg++) {
                        int row = row0 + wm + mi * 16 + 4 * q + reg;
                        float v = acc[mi][ni][reg];
                        float pv = __shfl_xor(v, 1, 64);   // partner column
                        float sn, cs;
                        sincosf((float)row * inv_freq, &sn, &cs);
                        Cq[(size_t)row * C_QKV + col] =
                            (__bf16)((v * cs + sgn * pv * sn) * osc);
                    }
                } else {
                    const int d = r - 320;
#pragma unroll
                    for (int reg = 0; reg < 4; reg++) {
                        int row = row0 + wm + mi * 16 + 4 * q + reg;
                        Vt[(size_t)(gg * 64 + d) * T_SEQ + row] =
                            (__bf16)acc[mi][ni][reg];
                    }
                }
            }
        }
}

// ---------------------------------------------------------------------------
// MFMA flash attention — transposed dataflow + SPLIT-K, no-atomics variant.
// r14: 2-wave blocks (128 threads), each wave spans 32 q-cols (was 4 waves x
// 16 q-cols). Every kb/vb LDS fragment now feeds TWO MFMAs instead of one:
// per wave per kv-tile = 20 ds_read_b128 + 8 ds_write_b64 per 32 MFMAs
// (was 18 + 4 per 16) -> LDS-read demand drops 8.3x-over-peak -> 5.0x.
// Grid, split-K balance, workspace reuse, merge: UNCHANGED from r12/r13
// winner. LDS/block still 41 KB -> 3 blocks/CU (6 waves/CU).
//
// grid (48,16):
//   x in [0,16):  qb = 15-x, full range, normalizes and writes y directly.
//   x in [16,32): qb = x,    kv tiles [0, (qb+2)/2)    -> half-0 partials
//   x in [32,48): qb = x-16, kv tiles [(qb+2)/2, qb+1) -> half-1 partials
// Partials: UNNORMALIZED bf16 O-half (plain stores, disjoint buffers) +
// fp32 l-half, stored in the x_bf / waT regions (dead after GEMM1).
// Co-resident triples {x, x+16, x+32} -> 33 tiles for ALL x: balanced at
// 3 blocks/CU. Body: S^T=K*Q^T, O^T=V^T*P^T, XOR-swizzled dbuf async
// staging, exp2 with pre-scaled q, wave-private Ps rows (no inner barrier).
// ---------------------------------------------------------------------------
__global__ __launch_bounds__(128) void attn_mfma_kernel(
    const __bf16* __restrict__ qkv, const __bf16* __restrict__ Vt,
    __bf16* __restrict__ y, __bf16* __restrict__ Opart,
    float* __restrict__ lpart)
{
    __shared__ __align__(16) __bf16 Ks0[64 * 64], Ks1[64 * 64];
    __shared__ __align__(16) __bf16 Vs0[64 * 64], Vs1[64 * 64];
    __shared__ __align__(16) __bf16 Ps[64 * 72];

    const int tid = threadIdx.x;
    const int l = tid & 63, w = tid >> 6;      // w in {0,1}
    const int ln = l & 15, q = l >> 4;
    const int x = blockIdx.x, h = blockIdx.y;
    int qb, t0, t1;
    bool partial;
    if (x < 16)      { qb = 15 - x;  t0 = 0;             t1 = qb + 1;        partial = false; }
    else if (x < 32) { qb = x;       t0 = 0;             t1 = (qb + 2) >> 1; partial = true;  }
    else             { qb = x - 16;  t0 = (qb + 2) >> 1; t1 = qb + 1;        partial = true;  }

    const int g = h >> 2, hj = h & 3;
    const int qbase = g * 384 + hj * 64;
    const int kbase = g * 384 + 256;

    // Q frags (B operand: B[k=d][n=qcol]); wave w owns q-cols [32w, 32w+32)
    // of the 64-row q-tile, as 2 groups (qj) of 16. Pre-scaled 0.125*log2e.
    bf16x8 qa[2][2];
#pragma unroll
    for (int qj = 0; qj < 2; qj++) {
        const int qrow = qb * 64 + w * 32 + qj * 16 + ln;
#pragma unroll
        for (int ki = 0; ki < 2; ki++)
            qa[qj][ki] = *(const bf16x8*)(qkv + (size_t)qrow * C_QKV + qbase +
                                          ki * 32 + q * 8);
    }

    f32x4 O[2][4];   // O^T: O[qj][ni][reg] = out[d = ni*16+4q+reg][qcol(qj)]
#pragma unroll
    for (int qj = 0; qj < 2; qj++)
#pragma unroll
        for (int ni = 0; ni < 4; ni++) O[qj][ni] = (f32x4){0.f, 0.f, 0.f, 0.f};
    float lsum[2] = {0.f, 0.f};

    auto stage = [&](int kt, __bf16* ks, __bf16* vs) {
#pragma unroll
        for (int p = 0; p < 4; p++) {
            int r = p * 16 + w * 8 + (l >> 3);
            int cc = (l & 7) ^ (r & 7);
            load_lds16(qkv + (size_t)(kt * 64 + r) * C_QKV + kbase + cc * 8,
                       ks + p * 1024 + w * 512);
            load_lds16(Vt + (size_t)(g * 64 + r) * T_SEQ + kt * 64 + cc * 8,
                       vs + p * 1024 + w * 512);
        }
    };
    auto compute = [&](int kt, const __bf16* ks, const __bf16* vs) {
        // S^T = K Q^T  (16 MFMAs; each kb read feeds both qj groups)
        f32x4 s[2][4];
#pragma unroll
        for (int qj = 0; qj < 2; qj++)
#pragma unroll
            for (int ni = 0; ni < 4; ni++) s[qj][ni] = (f32x4){0.f, 0.f, 0.f, 0.f};
#pragma unroll
        for (int ki = 0; ki < 2; ki++)
#pragma unroll
            for (int ni = 0; ni < 4; ni++) {
                bf16x8 kb = *(const bf16x8*)&ks[(ni * 16 + ln) * 64 +
                                                (((ki * 4 + q) ^ (ln & 7)) * 8)];
#pragma unroll
                for (int qj = 0; qj < 2; qj++)
                    s[qj][ni] = __builtin_amdgcn_mfma_f32_16x16x32_bf16(
                        kb, qa[qj][ki], s[qj][ni], 0, 0, 0);
            }

        // mask + exp2 + scalar l partials + packed b64 P store
        const bool diag = (kt == qb);
#pragma unroll
        for (int qj = 0; qj < 2; qj++)
#pragma unroll
            for (int ni = 0; ni < 4; ni++) {
                bf16x4 pp;
#pragma unroll
                for (int reg = 0; reg < 4; reg++) {
                    float v = s[qj][ni][reg];
                    if (diag && (ni * 16 + 4 * q + reg) > (w * 32 + qj * 16 + ln))
                        v = -1e30f;
                    float p = exp2f(v);               // masked -> exactly 0
                    lsum[qj] += p;
                    pp[reg] = (__bf16)p;
                }
                *(bf16x4*)&Ps[(w * 32 + qj * 16 + ln) * 72 + ni * 16 + 4 * q] = pp;
            }

        // O^T += V^T P^T (16 MFMAs; each vb read feeds both qj groups;
        // Ps rows wave-private -> no barrier)
#pragma unroll
        for (int ki = 0; ki < 2; ki++) {
            bf16x8 pa[2];
#pragma unroll
            for (int qj = 0; qj < 2; qj++)
                pa[qj] = *(const bf16x8*)&Ps[(w * 32 + qj * 16 + ln) * 72 +
                                             ki * 32 + q * 8];
#pragma unroll
            for (int ni = 0; ni < 4; ni++) {
                bf16x8 vb = *(const bf16x8*)&vs[(ni * 16 + ln) * 64 +
                                                (((ki * 4 + q) ^ (ln & 7)) * 8)];
#pragma unroll
                for (int qj = 0; qj < 2; qj++)
                    O[qj][ni] = __builtin_amdgcn_mfma_f32_16x16x32_bf16(
                        vb, pa[qj], O[qj][ni], 0, 0, 0);
            }
        }
    };

    stage(t0, Ks0, Vs0);
    for (int kt = t0;;) {
        __syncthreads();                      // buf0 fill drained; buf1 reads done
        if (kt + 1 < t1) stage(kt + 1, Ks1, Vs1);
        compute(kt, Ks0, Vs0);
        if (++kt >= t1) break;
        __syncthreads();                      // buf1 fill drained; buf0 reads done
        if (kt + 1 < t1) stage(kt + 1, Ks0, Vs0);
        compute(kt, Ks1, Vs1);
        if (++kt >= t1) break;
    }

#pragma unroll
    for (int qj = 0; qj < 2; qj++) {
        // l: reduce across the 4 quads holding row qcol=ln of group qj
        float ls = lsum[qj];
        ls += __shfl_xor(ls, 16, 64);
        ls += __shfl_xor(ls, 32, 64);
        const int t = qb * 64 + w * 32 + qj * 16 + ln;

        if (!partial) {
            const float inv = 1.0f / ls;
#pragma unroll
            for (int ni = 0; ni < 4; ni++) {
                bf16x4 o;
#pragma unroll
                for (int reg = 0; reg < 4; reg++) o[reg] = (__bf16)(O[qj][ni][reg] * inv);
                *(bf16x4*)&y[(size_t)t * C_EMB + h * 64 + ni * 16 + 4 * q] = o;
            }
        } else {
            // unnormalized bf16 partials to disjoint half-buffers (t >= 1024)
            const int half = (x >= 32);
            const int tr = t - 1024;
            __bf16* od = Opart + (size_t)half * 1024 * C_EMB +
                         (size_t)tr * C_EMB + h * 64;
            if (q == 0) lpart[half * 16 * 1024 + h * 1024 + tr] = ls;
#pragma unroll
            for (int ni = 0; ni < 4; ni++) {
                bf16x4 o;
#pragma unroll
                for (int reg = 0; reg < 4; reg++) o[reg] = (__bf16)O[qj][ni][reg];
                *(bf16x4*)&od[ni * 16 + 4 * q] = o;
            }
        }
    }
}

// ---------------------------------------------------------------------------
// Merge split-K halves: y[t][c] = (O_a+O_b)/(l_a+l_b) for t in [1024,2048).
// 512 blocks x 256 threads x 8 elems. Pure elementwise + per-row l lookup.
// ---------------------------------------------------------------------------
__global__ __launch_bounds__(256) void merge_kernel(
    const __bf16* __restrict__ Opart, const float* __restrict__ lpart,
    __bf16* __restrict__ y)
{
    const size_t base = ((size_t)blockIdx.x * 256 + threadIdx.x) * 8;
    const int tr = (int)(base >> 10);         // t - 1024
    const int c = (int)(base & 1023);
    const int h = c >> 6;
    const float inv = 1.0f / (lpart[h * 1024 + tr] +
                              lpart[16 * 1024 + h * 1024 + tr]);
    bf16x8 a = *(const bf16x8*)&Opart[base];
    bf16x8 b = *(const bf16x8*)&Opart[(size_t)1024 * C_EMB + base];
    bf16x8 o;
#pragma unroll
    for (int i = 0; i < 8; i++)
        o[i] = (__bf16)(((float)a[i] + (float)b[i]) * inv);
    *(bf16x8*)&y[(size_t)(1024 + tr) * C_EMB + c] = o;
}

// ---------------------------------------------------------------------------
extern "C" void kernel_launch(void* const* d_in, const int* in_sizes, int n_in,
                              void* d_out, int out_size, void* d_ws, size_t ws_size,
                              hipStream_t stream)
{
    const float* x      = (const float*)d_in[0];
    const float* w_attn = (const float*)d_in[1];
    const float* w_proj = (const float*)d_in[2];
    float* out = (float*)d_out;

    // Workspace: exactly 20 MiB (the r3..r12-proven footprint).
    __bf16* x_bf = (__bf16*)d_ws;                      // 2048x1024  4 MiB
    __bf16* waT  = x_bf + (size_t)T_SEQ * C_EMB;       // 1536x1024  3 MiB
    __bf16* wpT  = waT  + (size_t)C_QKV * C_EMB;       // 1024x1024  2 MiB
    __bf16* qkv  = wpT  + (size_t)C_EMB * C_EMB;       // 2048x1536  6 MiB
    __bf16* Vt   = qkv  + (size_t)T_SEQ * C_QKV;       // 256x2048   1 MiB
    __bf16* y_bf = Vt   + (size_t)256 * T_SEQ;         // 2048x1024  4 MiB
    // Split-K partials REUSE regions dead after GEMM1:
    __bf16* Opart = x_bf;           // 2 x 1024x1024 bf16 = 4 MiB (x_bf region)
    float*  lpart = (float*)waT;    // 2 x 16x1024 fp32 = 128 KB (waT region)

    prep_kernel<<<896, 256, 0, stream>>>(x, w_attn, w_proj, x_bf, waT, wpT);

    // GEMM1 + fused RoPE (+ q softmax/log2e pre-scale) + V-transpose scatter
    gemm_mfma_kernel<true><<<dim3(C_QKV / 64, T_SEQ / 64), 256, 0, stream>>>(
        x_bf, waT, qkv, Vt, nullptr, T_SEQ, C_QKV, C_EMB);

    attn_mfma_kernel<<<dim3(48, N_HEAD), 128, 0, stream>>>(
        qkv, Vt, y_bf, Opart, lpart);

    merge_kernel<<<512, 256, 0, stream>>>(Opart, lpart, y_bf);

    gemm_mfma_kernel<false><<<dim3(C_EMB / 64, T_SEQ / 64), 256, 0, stream>>>(
        y_bf, wpT, nullptr, nullptr, out, T_SEQ, C_EMB, C_EMB);
}

// Round 3
// 128.672 us; speedup vs baseline: 1.0037x; 1.0037x over previous
//
#include <hip/hip_runtime.h>

#define T_SEQ 2048
#define C_EMB 1024
#define C_QKV 1536
#define N_HEAD 16

typedef __bf16 bf16x8 __attribute__((ext_vector_type(8)));
typedef __bf16 bf16x4 __attribute__((ext_vector_type(4)));
typedef float  f32x4  __attribute__((ext_vector_type(4)));

// async 16B global -> LDS (global_load_lds_dwordx4).
// HW contract: LDS dest = wave-uniform base + lane*16B.
__device__ __forceinline__ void load_lds16(const __bf16* g, __bf16* l)
{
    __builtin_amdgcn_global_load_lds(
        (const __attribute__((address_space(1))) unsigned int*)g,
        (__attribute__((address_space(3))) unsigned int*)l, 16, 0, 0);
}

// ---------------------------------------------------------------------------
// Fused prep (r12 winner): blocks [0,384) transpose-convert w_attn,
// [384,640) w_proj, [640,896) grid-stride convert x.
// ---------------------------------------------------------------------------
__device__ __forceinline__ void tconv_tile(
    const float* __restrict__ in, __bf16* __restrict__ out,
    int R, int C, int r0, int c0, float (*lds)[65], int t)
{
#pragma unroll
    for (int k = 0; k < 16; k++) {
        int r = k * 4 + (t >> 6), c = t & 63;
        lds[r][c] = in[(size_t)(r0 + r) * C + c0 + c];
    }
    __syncthreads();
#pragma unroll
    for (int k = 0; k < 16; k++) {
        int cc = k * 4 + (t >> 6), rr = t & 63;
        out[(size_t)(c0 + cc) * R + r0 + rr] = (__bf16)lds[rr][cc];
    }
}

__global__ __launch_bounds__(256) void prep_kernel(
    const float* __restrict__ x, const float* __restrict__ wa,
    const float* __restrict__ wp, __bf16* __restrict__ x_bf,
    __bf16* __restrict__ waT, __bf16* __restrict__ wpT)
{
    __shared__ float lds[64][65];
    const int b = blockIdx.x, t = threadIdx.x;
    if (b < 384) {                      // w_attn [1024][1536] -> waT [1536][1024]
        tconv_tile(wa, waT, C_EMB, C_QKV, (b / 24) * 64, (b % 24) * 64, lds, t);
    } else if (b < 640) {               // w_proj [1024][1024] -> wpT [1024][1024]
        int b2 = b - 384;
        tconv_tile(wp, wpT, C_EMB, C_EMB, (b2 / 16) * 64, (b2 % 16) * 64, lds, t);
    } else {                            // x fp32 -> bf16
        for (int gi = (b - 640) * 256 + t; gi < T_SEQ * C_EMB / 8; gi += 65536) {
            float4 v0 = ((const float4*)x)[gi * 2];
            float4 v1 = ((const float4*)x)[gi * 2 + 1];
            bf16x8 o = { (__bf16)v0.x, (__bf16)v0.y, (__bf16)v0.z, (__bf16)v0.w,
                         (__bf16)v1.x, (__bf16)v1.y, (__bf16)v1.z, (__bf16)v1.w };
            ((bf16x8*)x_bf)[gi] = o;
        }
    }
}

// ---------------------------------------------------------------------------
// bf16 MFMA GEMM (r12 winner, unchanged): C = A(MxK) @ Bt(NxK)^T.
// 64x64 tile, BK=64, 4 waves (2x2), wave 32x32. GEMM1: 768 blocks = 3/CU,
// GEMM2: 512 = 2/CU. XOR-swizzled unpadded LDS + global_load_lds + dbuf.
// FUSE_QKV epilogue: RoPE (partner col via __shfl_xor(.,1)), q cols
// pre-scaled by 0.125*log2e, v cols scattered into Vt[g*64+d][t].
// ---------------------------------------------------------------------------
template <bool FUSE_QKV>
__global__ __launch_bounds__(256) void gemm_mfma_kernel(
    const __bf16* __restrict__ A, const __bf16* __restrict__ Bt,
    __bf16* __restrict__ Cq, __bf16* __restrict__ Vt,
    float* __restrict__ Cf, int M, int N, int K)
{
    __shared__ __align__(16) __bf16 As0[64 * 64], As1[64 * 64];
    __shared__ __align__(16) __bf16 Bs0[64 * 64], Bs1[64 * 64];

    const int tid = threadIdx.x;
    const int l = tid & 63, w = tid >> 6;
    const int ln = l & 15, q = l >> 4;
    const int wm = (w & 1) * 32, wn = (w >> 1) * 32;
    const int row0 = blockIdx.y * 64, col0 = blockIdx.x * 64;

    f32x4 acc[2][2];
#pragma unroll
    for (int mi = 0; mi < 2; mi++)
#pragma unroll
        for (int ni = 0; ni < 2; ni++) acc[mi][ni] = (f32x4){0.f, 0.f, 0.f, 0.f};

    auto stage = [&](int k0, __bf16* as, __bf16* bs) {
#pragma unroll
        for (int p = 0; p < 2; p++) {
            int r = p * 32 + w * 8 + (l >> 3);
            int cc = (l & 7) ^ (r & 7);           // swizzled source chunk
            load_lds16(A + (size_t)(row0 + r) * K + k0 + cc * 8,
                       as + p * 2048 + w * 512);  // wave-uniform base
            load_lds16(Bt + (size_t)(col0 + r) * K + k0 + cc * 8,
                       bs + p * 2048 + w * 512);
        }
    };
    auto compute = [&](const __bf16* as, const __bf16* bs) {
#pragma unroll
        for (int ki = 0; ki < 2; ki++) {
            bf16x8 af[2], bfr[2];
#pragma unroll
            for (int mi = 0; mi < 2; mi++)
                af[mi] = *(const bf16x8*)&as[(wm + mi * 16 + ln) * 64 +
                                             (((ki * 4 + q) ^ (ln & 7)) * 8)];
#pragma unroll
            for (int ni = 0; ni < 2; ni++)
                bfr[ni] = *(const bf16x8*)&bs[(wn + ni * 16 + ln) * 64 +
                                              (((ki * 4 + q) ^ (ln & 7)) * 8)];
#pragma unroll
            for (int mi = 0; mi < 2; mi++)
#pragma unroll
                for (int ni = 0; ni < 2; ni++)
                    acc[mi][ni] = __builtin_amdgcn_mfma_f32_16x16x32_bf16(
                        af[mi], bfr[ni], acc[mi][ni], 0, 0, 0);
        }
    };

    stage(0, As0, Bs0);
    for (int k0 = 0;; k0 += 128) {
        __syncthreads();                      // buf0 fill drained
        if (k0 + 64 < K) stage(k0 + 64, As1, Bs1);
        compute(As0, Bs0);
        if (k0 + 64 >= K) break;
        __syncthreads();                      // buf1 fill drained
        if (k0 + 128 < K) stage(k0 + 128, As0, Bs0);
        compute(As1, Bs1);
        if (k0 + 128 >= K) break;
    }

    // C/D layout: col = lane&15, row = quad*4 + reg
#pragma unroll
    for (int mi = 0; mi < 2; mi++)
#pragma unroll
        for (int ni = 0; ni < 2; ni++) {
            const int col = col0 + wn + ni * 16 + ln;
            if (!FUSE_QKV) {
#pragma unroll
                for (int reg = 0; reg < 4; reg++) {
                    int row = row0 + wm + mi * 16 + 4 * q + reg;
                    Cf[(size_t)row * N + col] = acc[mi][ni][reg];
                }
            } else {
                // per-group col layout (384): q [0,256), k [256,320), v [320,384)
                const int r = col % 384;
                const int gg = col / 384;
                if (r < 320) {
                    const int d = r & 63;
                    const float inv_freq =
                        __expf(-(float)(d & ~1) * (9.210340371976184f / 64.0f));
                    const float sgn = (d & 1) ? 1.0f : -1.0f;
                    const float osc = (r < 256) ? 0.18033688011112042f : 1.0f;
#pragma unroll
                    for (int reg = 0; reg < 4; reg++) {
                        int row = row0 + wm + mi * 16 + 4 * q + reg;
                        float v = acc[mi][ni][reg];
                        float pv = __shfl_xor(v, 1, 64);   // partner column
                        float sn, cs;
                        sincosf((float)row * inv_freq, &sn, &cs);
                        Cq[(size_t)row * C_QKV + col] =
                            (__bf16)((v * cs + sgn * pv * sn) * osc);
                    }
                } else {
                    const int d = r - 320;
#pragma unroll
                    for (int reg = 0; reg < 4; reg++) {
                        int row = row0 + wm + mi * 16 + 4 * q + reg;
                        Vt[(size_t)(gg * 64 + d) * T_SEQ + row] =
                            (__bf16)acc[mi][ni][reg];
                    }
                }
            }
        }
}

// ---------------------------------------------------------------------------
// MFMA flash attention — r15: 128-row Q-tile, 4 waves x 32 q-cols, 256 thr.
// Keeps r14's proven 2-qj fragment-reuse body (each kb/vb LDS read feeds 2
// MFMAs; 20 ds_read_b128 + 8 ds_write_b64 per 32 wave-MFMAs) but at FULL
// 4-wave blocks: 50 KB LDS -> 2 blocks/CU = 8 waves/CU, and barriers per
// wave-MFMA halved vs r12 (1 barrier / 32 MFMAs).
//
// Work split (EXACT per-CU balance): 1-D grid 512. b -> rep=b>>8, u=b&255,
// head=u&15, s=u>>4.
//   rep0: qb=s,    kv tiles [0, qb+1)        -> unnorm O into y, l into l0
//   rep1: qb=15-s, kv tiles [qb+1, 2*qb+2)   -> unnorm O into Opart, l1
// Co-resident pair (b, b+256) [same CU, +256 block-id step]: same s ->
// (s+1) + (16-s) = 17 tiles on EVERY CU. Both halves of every row are
// unnormalized bf16 sums (no-max softmax => pure sums; exact 2-way merge).
// Partials live in regions dead after GEMM1 (y_bf itself + x_bf + waT):
// workspace stays 20 MiB. Diagonal: tile kt, rel=kt-2*qb; mask element when
// rel*64 + krow > local qrow (auto-false for rel<0).
// ---------------------------------------------------------------------------
__global__ __launch_bounds__(256) void attn_mfma_kernel(
    const __bf16* __restrict__ qkv, const __bf16* __restrict__ Vt,
    __bf16* __restrict__ y, __bf16* __restrict__ Opart,
    float* __restrict__ lpart)
{
    __shared__ __align__(16) __bf16 Ks0[64 * 64], Ks1[64 * 64];
    __shared__ __align__(16) __bf16 Vs0[64 * 64], Vs1[64 * 64];
    __shared__ __align__(16) __bf16 Ps[128 * 72];

    const int tid = threadIdx.x;
    const int l = tid & 63, w = tid >> 6;      // w in {0..3}
    const int ln = l & 15, q = l >> 4;

    const int b = blockIdx.x;
    const int rep = b >> 8, u = b & 255;
    const int h = u & 15, s0 = u >> 4;         // s0 in [0,16)
    const int qb = rep ? (15 - s0) : s0;
    const int t0 = rep ? (qb + 1) : 0;
    const int t1 = rep ? (2 * qb + 2) : (qb + 1);
    const int qb2 = qb * 2;

    const int g = h >> 2, hj = h & 3;
    const int qbase = g * 384 + hj * 64;
    const int kbase = g * 384 + 256;

    // Q frags (B operand: B[k=d][n=qcol]); wave w owns q-cols [32w, 32w+32)
    // of the 128-row q-tile, as 2 groups (qj) of 16. Pre-scaled 0.125*log2e.
    bf16x8 qa[2][2];
#pragma unroll
    for (int qj = 0; qj < 2; qj++) {
        const int qrow = qb * 128 + w * 32 + qj * 16 + ln;
#pragma unroll
        for (int ki = 0; ki < 2; ki++)
            qa[qj][ki] = *(const bf16x8*)(qkv + (size_t)qrow * C_QKV + qbase +
                                          ki * 32 + q * 8);
    }

    f32x4 O[2][4];   // O^T: O[qj][ni][reg] = out[d = ni*16+4q+reg][qcol(qj)]
#pragma unroll
    for (int qj = 0; qj < 2; qj++)
#pragma unroll
        for (int ni = 0; ni < 4; ni++) O[qj][ni] = (f32x4){0.f, 0.f, 0.f, 0.f};
    float lsum[2] = {0.f, 0.f};

    auto stage = [&](int kt, __bf16* ks, __bf16* vs) {
#pragma unroll
        for (int p = 0; p < 2; p++) {
            int r = p * 32 + w * 8 + (l >> 3);
            int cc = (l & 7) ^ (r & 7);
            load_lds16(qkv + (size_t)(kt * 64 + r) * C_QKV + kbase + cc * 8,
                       ks + p * 2048 + w * 512);
            load_lds16(Vt + (size_t)(g * 64 + r) * T_SEQ + kt * 64 + cc * 8,
                       vs + p * 2048 + w * 512);
        }
    };
    auto compute = [&](int kt, const __bf16* ks, const __bf16* vs) {
        // S^T = K Q^T  (16 MFMAs; each kb read feeds both qj groups)
        f32x4 sc[2][4];
#pragma unroll
        for (int qj = 0; qj < 2; qj++)
#pragma unroll
            for (int ni = 0; ni < 4; ni++) sc[qj][ni] = (f32x4){0.f, 0.f, 0.f, 0.f};
#pragma unroll
        for (int ki = 0; ki < 2; ki++)
#pragma unroll
            for (int ni = 0; ni < 4; ni++) {
                bf16x8 kb = *(const bf16x8*)&ks[(ni * 16 + ln) * 64 +
                                                (((ki * 4 + q) ^ (ln & 7)) * 8)];
#pragma unroll
                for (int qj = 0; qj < 2; qj++)
                    sc[qj][ni] = __builtin_amdgcn_mfma_f32_16x16x32_bf16(
                        kb, qa[qj][ki], sc[qj][ni], 0, 0, 0);
            }

        // mask + exp2 + scalar l partials + packed b64 P store
        const int rel = kt - qb2;              // >=0 only on diagonal band
        const int koff = rel * 64;
#pragma unroll
        for (int qj = 0; qj < 2; qj++) {
            const int qr = w * 32 + qj * 16 + ln;
#pragma unroll
            for (int ni = 0; ni < 4; ni++) {
                bf16x4 pp;
#pragma unroll
                for (int reg = 0; reg < 4; reg++) {
                    float v = sc[qj][ni][reg];
                    if (rel >= 0 && (koff + ni * 16 + 4 * q + reg) > qr)
                        v = -1e30f;
                    float p = exp2f(v);               // masked -> exactly 0
                    lsum[qj] += p;
                    pp[reg] = (__bf16)p;
                }
                *(bf16x4*)&Ps[(qr)*72 + ni * 16 + 4 * q] = pp;
            }
        }

        // O^T += V^T P^T (16 MFMAs; each vb read feeds both qj groups;
        // Ps rows wave-private -> no barrier)
#pragma unroll
        for (int ki = 0; ki < 2; ki++) {
            bf16x8 pa[2];
#pragma unroll
            for (int qj = 0; qj < 2; qj++)
                pa[qj] = *(const bf16x8*)&Ps[(w * 32 + qj * 16 + ln) * 72 +
                                             ki * 32 + q * 8];
#pragma unroll
            for (int ni = 0; ni < 4; ni++) {
                bf16x8 vb = *(const bf16x8*)&vs[(ni * 16 + ln) * 64 +
                                                (((ki * 4 + q) ^ (ln & 7)) * 8)];
#pragma unroll
                for (int qj = 0; qj < 2; qj++)
                    O[qj][ni] = __builtin_amdgcn_mfma_f32_16x16x32_bf16(
                        vb, pa[qj], O[qj][ni], 0, 0, 0);
            }
        }
    };

    stage(t0, Ks0, Vs0);
    for (int kt = t0;;) {
        __syncthreads();                      // buf0 fill drained; buf1 reads done
        if (kt + 1 < t1) stage(kt + 1, Ks1, Vs1);
        compute(kt, Ks0, Vs0);
        if (++kt >= t1) break;
        __syncthreads();                      // buf1 fill drained; buf0 reads done
        if (kt + 1 < t1) stage(kt + 1, Ks0, Vs0);
        compute(kt, Ks1, Vs1);
        if (++kt >= t1) break;
    }

    // Unnormalized bf16 partial O + fp32 l, to disjoint per-rep buffers.
#pragma unroll
    for (int qj = 0; qj < 2; qj++) {
        // l: reduce across the 4 quads holding qcol=ln of group qj
        float ls = lsum[qj];
        ls += __shfl_xor(ls, 16, 64);
        ls += __shfl_xor(ls, 32, 64);
        const int t = qb * 128 + w * 32 + qj * 16 + ln;
        __bf16* od = (rep ? Opart : y) + (size_t)t * C_EMB + h * 64;
        if (q == 0) lpart[rep * 16 * 2048 + h * 2048 + t] = ls;
#pragma unroll
        for (int ni = 0; ni < 4; ni++) {
            bf16x4 o;
#pragma unroll
            for (int reg = 0; reg < 4; reg++) o[reg] = (__bf16)O[qj][ni][reg];
            *(bf16x4*)&od[ni * 16 + 4 * q] = o;
        }
    }
}

// ---------------------------------------------------------------------------
// Merge split-K halves IN PLACE over all rows:
// y[t][c] = (y_unnorm[t][c] + Opart[t][c]) / (l0[t]+l1[t]).
// 1024 blocks x 256 threads x 8 elems.
// ---------------------------------------------------------------------------
__global__ __launch_bounds__(256) void merge_kernel(
    const __bf16* __restrict__ Opart, const float* __restrict__ lpart,
    __bf16* __restrict__ y)
{
    const size_t base = ((size_t)blockIdx.x * 256 + threadIdx.x) * 8;
    const int t = (int)(base >> 10);
    const int c = (int)(base & 1023);
    const int h = c >> 6;
    const float inv = 1.0f / (lpart[h * 2048 + t] +
                              lpart[16 * 2048 + h * 2048 + t]);
    bf16x8 a = *(const bf16x8*)&y[base];
    bf16x8 bb = *(const bf16x8*)&Opart[base];
    bf16x8 o;
#pragma unroll
    for (int i = 0; i < 8; i++)
        o[i] = (__bf16)(((float)a[i] + (float)bb[i]) * inv);
    *(bf16x8*)&y[base] = o;
}

// ---------------------------------------------------------------------------
extern "C" void kernel_launch(void* const* d_in, const int* in_sizes, int n_in,
                              void* d_out, int out_size, void* d_ws, size_t ws_size,
                              hipStream_t stream)
{
    const float* x      = (const float*)d_in[0];
    const float* w_attn = (const float*)d_in[1];
    const float* w_proj = (const float*)d_in[2];
    float* out = (float*)d_out;

    // Workspace: exactly 20 MiB (the r3..r12-proven footprint).
    __bf16* x_bf = (__bf16*)d_ws;                      // 2048x1024  4 MiB
    __bf16* waT  = x_bf + (size_t)T_SEQ * C_EMB;       // 1536x1024  3 MiB
    __bf16* wpT  = waT  + (size_t)C_QKV * C_EMB;       // 1024x1024  2 MiB
    __bf16* qkv  = wpT  + (size_t)C_EMB * C_EMB;       // 2048x1536  6 MiB
    __bf16* Vt   = qkv  + (size_t)T_SEQ * C_QKV;       // 256x2048   1 MiB
    __bf16* y_bf = Vt   + (size_t)256 * T_SEQ;         // 2048x1024  4 MiB
    // Split-K partials REUSE regions dead after GEMM1:
    __bf16* Opart = x_bf;           // 2048x1024 bf16 = 4 MiB (x_bf region)
    float*  lpart = (float*)waT;    // 2 x 16x2048 fp32 = 256 KB (waT region)

    prep_kernel<<<896, 256, 0, stream>>>(x, w_attn, w_proj, x_bf, waT, wpT);

    // GEMM1 + fused RoPE (+ q softmax/log2e pre-scale) + V-transpose scatter
    gemm_mfma_kernel<true><<<dim3(C_QKV / 64, T_SEQ / 64), 256, 0, stream>>>(
        x_bf, waT, qkv, Vt, nullptr, T_SEQ, C_QKV, C_EMB);

    attn_mfma_kernel<<<512, 256, 0, stream>>>(
        qkv, Vt, y_bf, Opart, lpart);

    merge_kernel<<<1024, 256, 0, stream>>>(Opart, lpart, y_bf);

    gemm_mfma_kernel<false><<<dim3(C_EMB / 64, T_SEQ / 64), 256, 0, stream>>>(
        y_bf, wpT, nullptr, nullptr, out, T_SEQ, C_EMB, C_EMB);
}

// Round 4
// 119.823 us; speedup vs baseline: 1.0779x; 1.0739x over previous
//
#include <hip/hip_runtime.h>

#define T_SEQ 2048
#define C_EMB 1024
#define C_QKV 1536
#define N_HEAD 16

typedef __bf16 bf16x8 __attribute__((ext_vector_type(8)));
typedef __bf16 bf16x4 __attribute__((ext_vector_type(4)));
typedef float  f32x4  __attribute__((ext_vector_type(4)));

// async 16B global -> LDS (global_load_lds_dwordx4).
// HW contract: LDS dest = wave-uniform base + lane*16B.
__device__ __forceinline__ void load_lds16(const __bf16* g, __bf16* l)
{
    __builtin_amdgcn_global_load_lds(
        (const __attribute__((address_space(1))) unsigned int*)g,
        (__attribute__((address_space(3))) unsigned int*)l, 16, 0, 0);
}

// ---------------------------------------------------------------------------
// Fused prep (r12 winner): blocks [0,384) transpose-convert w_attn,
// [384,640) w_proj, [640,896) grid-stride convert x.
// ---------------------------------------------------------------------------
__device__ __forceinline__ void tconv_tile(
    const float* __restrict__ in, __bf16* __restrict__ out,
    int R, int C, int r0, int c0, float (*lds)[65], int t)
{
#pragma unroll
    for (int k = 0; k < 16; k++) {
        int r = k * 4 + (t >> 6), c = t & 63;
        lds[r][c] = in[(size_t)(r0 + r) * C + c0 + c];
    }
    __syncthreads();
#pragma unroll
    for (int k = 0; k < 16; k++) {
        int cc = k * 4 + (t >> 6), rr = t & 63;
        out[(size_t)(c0 + cc) * R + r0 + rr] = (__bf16)lds[rr][cc];
    }
}

__global__ __launch_bounds__(256) void prep_kernel(
    const float* __restrict__ x, const float* __restrict__ wa,
    const float* __restrict__ wp, __bf16* __restrict__ x_bf,
    __bf16* __restrict__ waT, __bf16* __restrict__ wpT)
{
    __shared__ float lds[64][65];
    const int b = blockIdx.x, t = threadIdx.x;
    if (b < 384) {                      // w_attn [1024][1536] -> waT [1536][1024]
        tconv_tile(wa, waT, C_EMB, C_QKV, (b / 24) * 64, (b % 24) * 64, lds, t);
    } else if (b < 640) {               // w_proj [1024][1024] -> wpT [1024][1024]
        int b2 = b - 384;
        tconv_tile(wp, wpT, C_EMB, C_EMB, (b2 / 16) * 64, (b2 % 16) * 64, lds, t);
    } else {                            // x fp32 -> bf16
        for (int gi = (b - 640) * 256 + t; gi < T_SEQ * C_EMB / 8; gi += 65536) {
            float4 v0 = ((const float4*)x)[gi * 2];
            float4 v1 = ((const float4*)x)[gi * 2 + 1];
            bf16x8 o = { (__bf16)v0.x, (__bf16)v0.y, (__bf16)v0.z, (__bf16)v0.w,
                         (__bf16)v1.x, (__bf16)v1.y, (__bf16)v1.z, (__bf16)v1.w };
            ((bf16x8*)x_bf)[gi] = o;
        }
    }
}

// ---------------------------------------------------------------------------
// bf16 MFMA GEMM (r12 winner, unchanged): C = A(MxK) @ Bt(NxK)^T.
// 64x64 tile, BK=64, 4 waves (2x2), wave 32x32. GEMM1: 768 blocks = 3/CU,
// GEMM2: 512 = 2/CU. XOR-swizzled unpadded LDS + global_load_lds + dbuf.
// FUSE_QKV epilogue: RoPE (partner col via __shfl_xor(.,1)), q cols
// pre-scaled by 0.125*log2e, v cols scattered into Vt[g*64+d][t].
// ---------------------------------------------------------------------------
template <bool FUSE_QKV>
__global__ __launch_bounds__(256) void gemm_mfma_kernel(
    const __bf16* __restrict__ A, const __bf16* __restrict__ Bt,
    __bf16* __restrict__ Cq, __bf16* __restrict__ Vt,
    float* __restrict__ Cf, int M, int N, int K)
{
    __shared__ __align__(16) __bf16 As0[64 * 64], As1[64 * 64];
    __shared__ __align__(16) __bf16 Bs0[64 * 64], Bs1[64 * 64];

    const int tid = threadIdx.x;
    const int l = tid & 63, w = tid >> 6;
    const int ln = l & 15, q = l >> 4;
    const int wm = (w & 1) * 32, wn = (w >> 1) * 32;
    const int row0 = blockIdx.y * 64, col0 = blockIdx.x * 64;

    f32x4 acc[2][2];
#pragma unroll
    for (int mi = 0; mi < 2; mi++)
#pragma unroll
        for (int ni = 0; ni < 2; ni++) acc[mi][ni] = (f32x4){0.f, 0.f, 0.f, 0.f};

    auto stage = [&](int k0, __bf16* as, __bf16* bs) {
#pragma unroll
        for (int p = 0; p < 2; p++) {
            int r = p * 32 + w * 8 + (l >> 3);
            int cc = (l & 7) ^ (r & 7);           // swizzled source chunk
            load_lds16(A + (size_t)(row0 + r) * K + k0 + cc * 8,
                       as + p * 2048 + w * 512);  // wave-uniform base
            load_lds16(Bt + (size_t)(col0 + r) * K + k0 + cc * 8,
                       bs + p * 2048 + w * 512);
        }
    };
    auto compute = [&](const __bf16* as, const __bf16* bs) {
#pragma unroll
        for (int ki = 0; ki < 2; ki++) {
            bf16x8 af[2], bfr[2];
#pragma unroll
            for (int mi = 0; mi < 2; mi++)
                af[mi] = *(const bf16x8*)&as[(wm + mi * 16 + ln) * 64 +
                                             (((ki * 4 + q) ^ (ln & 7)) * 8)];
#pragma unroll
            for (int ni = 0; ni < 2; ni++)
                bfr[ni] = *(const bf16x8*)&bs[(wn + ni * 16 + ln) * 64 +
                                              (((ki * 4 + q) ^ (ln & 7)) * 8)];
#pragma unroll
            for (int mi = 0; mi < 2; mi++)
#pragma unroll
                for (int ni = 0; ni < 2; ni++)
                    acc[mi][ni] = __builtin_amdgcn_mfma_f32_16x16x32_bf16(
                        af[mi], bfr[ni], acc[mi][ni], 0, 0, 0);
        }
    };

    stage(0, As0, Bs0);
    for (int k0 = 0;; k0 += 128) {
        __syncthreads();                      // buf0 fill drained
        if (k0 + 64 < K) stage(k0 + 64, As1, Bs1);
        compute(As0, Bs0);
        if (k0 + 64 >= K) break;
        __syncthreads();                      // buf1 fill drained
        if (k0 + 128 < K) stage(k0 + 128, As0, Bs0);
        compute(As1, Bs1);
        if (k0 + 128 >= K) break;
    }

    // C/D layout: col = lane&15, row = quad*4 + reg
#pragma unroll
    for (int mi = 0; mi < 2; mi++)
#pragma unroll
        for (int ni = 0; ni < 2; ni++) {
            const int col = col0 + wn + ni * 16 + ln;
            if (!FUSE_QKV) {
#pragma unroll
                for (int reg = 0; reg < 4; reg++) {
                    int row = row0 + wm + mi * 16 + 4 * q + reg;
                    Cf[(size_t)row * N + col] = acc[mi][ni][reg];
                }
            } else {
                // per-group col layout (384): q [0,256), k [256,320), v [320,384)
                const int r = col % 384;
                const int gg = col / 384;
                if (r < 320) {
                    const int d = r & 63;
                    const float inv_freq =
                        __expf(-(float)(d & ~1) * (9.210340371976184f / 64.0f));
                    const float sgn = (d & 1) ? 1.0f : -1.0f;
                    const float osc = (r < 256) ? 0.18033688011112042f : 1.0f;
#pragma unroll
                    for (int reg = 0; reg < 4; reg++) {
                        int row = row0 + wm + mi * 16 + 4 * q + reg;
                        float v = acc[mi][ni][reg];
                        float pv = __shfl_xor(v, 1, 64);   // partner column
                        float sn, cs;
                        sincosf((float)row * inv_freq, &sn, &cs);
                        Cq[(size_t)row * C_QKV + col] =
                            (__bf16)((v * cs + sgn * pv * sn) * osc);
                    }
                } else {
                    const int d = r - 320;
#pragma unroll
                    for (int reg = 0; reg < 4; reg++) {
                        int row = row0 + wm + mi * 16 + 4 * q + reg;
                        Vt[(size_t)(gg * 64 + d) * T_SEQ + row] =
                            (__bf16)acc[mi][ni][reg];
                    }
                }
            }
        }
}

// ---------------------------------------------------------------------------
// MFMA flash attention — transposed dataflow + SPLIT-K, no-atomics variant.
// Body = r12 winner EXACTLY (the 118.9 us anchor); r16 adds ONLY
// s_setprio(1)/(0) around the two MFMA clusters (T5: pays off when
// co-resident waves are at different phases — here 3 independent
// blocks/CU at staggered kv-tile positions).
// grid (48,16):
//   x in [0,16):  qb = 15-x, full range, normalizes and writes y directly.
//   x in [16,32): qb = x,    kv tiles [0, (qb+2)/2)    -> half-0 partials
//   x in [32,48): qb = x-16, kv tiles [(qb+2)/2, qb+1) -> half-1 partials
// Partials: UNNORMALIZED bf16 O-half (plain stores, disjoint buffers - no
// atomics, no zero-init, deterministic) + fp32 l-half. Stored in the x_bf /
// waT regions (dead after GEMM1). Co-resident triples {x, x+16, x+32}
// (+256 block-id steps, grid.x=48) -> per-CU work = (16-x)+(x+17) = 33
// tiles for ALL x: balanced at 3 blocks/CU (123 KB LDS), 12 waves/CU.
// ---------------------------------------------------------------------------
__global__ __launch_bounds__(256) void attn_mfma_kernel(
    const __bf16* __restrict__ qkv, const __bf16* __restrict__ Vt,
    __bf16* __restrict__ y, __bf16* __restrict__ Opart,
    float* __restrict__ lpart)
{
    __shared__ __align__(16) __bf16 Ks0[64 * 64], Ks1[64 * 64];
    __shared__ __align__(16) __bf16 Vs0[64 * 64], Vs1[64 * 64];
    __shared__ __align__(16) __bf16 Ps[64 * 72];

    const int tid = threadIdx.x;
    const int l = tid & 63, w = tid >> 6;
    const int ln = l & 15, q = l >> 4;
    const int x = blockIdx.x, h = blockIdx.y;
    int qb, t0, t1;
    bool partial;
    if (x < 16)      { qb = 15 - x;  t0 = 0;             t1 = qb + 1;        partial = false; }
    else if (x < 32) { qb = x;       t0 = 0;             t1 = (qb + 2) >> 1; partial = true;  }
    else             { qb = x - 16;  t0 = (qb + 2) >> 1; t1 = qb + 1;        partial = true;  }

    const int g = h >> 2, hj = h & 3;
    const int qbase = g * 384 + hj * 64;
    const int kbase = g * 384 + 256;

    // Q frag (B operand: B[k=d=quad*8+j][n=qrow=ln]); pre-scaled 0.125*log2e
    const int qrow = qb * 64 + w * 16 + ln;
    bf16x8 qa[2];
#pragma unroll
    for (int ki = 0; ki < 2; ki++)
        qa[ki] = *(const bf16x8*)(qkv + (size_t)qrow * C_QKV + qbase +
                                  ki * 32 + q * 8);

    f32x4 O[4];   // O^T: O[ni][reg] = out[d = ni*16+4q+reg][qrow = ln]
#pragma unroll
    for (int ni = 0; ni < 4; ni++) O[ni] = (f32x4){0.f, 0.f, 0.f, 0.f};
    float lsum = 0.f;

    auto stage = [&](int kt, __bf16* ks, __bf16* vs) {
#pragma unroll
        for (int p = 0; p < 2; p++) {
            int r = p * 32 + w * 8 + (l >> 3);
            int cc = (l & 7) ^ (r & 7);
            load_lds16(qkv + (size_t)(kt * 64 + r) * C_QKV + kbase + cc * 8,
                       ks + p * 2048 + w * 512);
            load_lds16(Vt + (size_t)(g * 64 + r) * T_SEQ + kt * 64 + cc * 8,
                       vs + p * 2048 + w * 512);
        }
    };
    auto compute = [&](int kt, const __bf16* ks, const __bf16* vs) {
        // S^T = K Q^T  (8 MFMAs)
        f32x4 s[4];
#pragma unroll
        for (int ni = 0; ni < 4; ni++) s[ni] = (f32x4){0.f, 0.f, 0.f, 0.f};
        __builtin_amdgcn_s_setprio(1);
#pragma unroll
        for (int ki = 0; ki < 2; ki++)
#pragma unroll
            for (int ni = 0; ni < 4; ni++) {
                bf16x8 kb = *(const bf16x8*)&ks[(ni * 16 + ln) * 64 +
                                                (((ki * 4 + q) ^ (ln & 7)) * 8)];
                s[ni] = __builtin_amdgcn_mfma_f32_16x16x32_bf16(
                    kb, qa[ki], s[ni], 0, 0, 0);
            }
        __builtin_amdgcn_s_setprio(0);

        // mask + exp2 + scalar l partial + packed b64 P store
        const bool diag = (kt == qb);
#pragma unroll
        for (int ni = 0; ni < 4; ni++) {
            bf16x4 pp;
#pragma unroll
            for (int reg = 0; reg < 4; reg++) {
                float v = s[ni][reg];
                if (diag && (ni * 16 + 4 * q + reg) > (w * 16 + ln)) v = -1e30f;
                float p = exp2f(v);               // masked -> exactly 0
                lsum += p;
                pp[reg] = (__bf16)p;
            }
            *(bf16x4*)&Ps[(w * 16 + ln) * 72 + ni * 16 + 4 * q] = pp;
        }

        // O^T += V^T P^T (8 MFMAs; Ps rows wave-private -> no barrier)
        __builtin_amdgcn_s_setprio(1);
#pragma unroll
        for (int ki = 0; ki < 2; ki++) {
            bf16x8 pa = *(const bf16x8*)&Ps[(w * 16 + ln) * 72 +
                                            ki * 32 + q * 8];
#pragma unroll
            for (int ni = 0; ni < 4; ni++) {
                bf16x8 vb = *(const bf16x8*)&vs[(ni * 16 + ln) * 64 +
                                                (((ki * 4 + q) ^ (ln & 7)) * 8)];
                O[ni] = __builtin_amdgcn_mfma_f32_16x16x32_bf16(
                    vb, pa, O[ni], 0, 0, 0);
            }
        }
        __builtin_amdgcn_s_setprio(0);
    };

    stage(t0, Ks0, Vs0);
    for (int kt = t0;;) {
        __syncthreads();                      // buf0 fill drained; buf1 reads done
        if (kt + 1 < t1) stage(kt + 1, Ks1, Vs1);
        compute(kt, Ks0, Vs0);
        if (++kt >= t1) break;
        __syncthreads();                      // buf1 fill drained; buf0 reads done
        if (kt + 1 < t1) stage(kt + 1, Ks0, Vs0);
        compute(kt, Ks1, Vs1);
        if (++kt >= t1) break;
    }

    // l: reduce across the 4 quads holding row qrow=ln (xor 16, 32)
    float ls = lsum;
    ls += __shfl_xor(ls, 16, 64);
    ls += __shfl_xor(ls, 32, 64);
    const int t = qb * 64 + w * 16 + ln;

    if (!partial) {
        const float inv = 1.0f / ls;
#pragma unroll
        for (int ni = 0; ni < 4; ni++) {
            bf16x4 o;
#pragma unroll
            for (int reg = 0; reg < 4; reg++) o[reg] = (__bf16)(O[ni][reg] * inv);
            *(bf16x4*)&y[(size_t)t * C_EMB + h * 64 + ni * 16 + 4 * q] = o;
        }
    } else {
        // unnormalized bf16 partials to disjoint half-buffers (t >= 1024)
        const int half = (x >= 32);
        const int tr = t - 1024;
        __bf16* od = Opart + (size_t)half * 1024 * C_EMB +
                     (size_t)tr * C_EMB + h * 64;
        if (q == 0) lpart[half * 16 * 1024 + h * 1024 + tr] = ls;
#pragma unroll
        for (int ni = 0; ni < 4; ni++) {
            bf16x4 o;
#pragma unroll
            for (int reg = 0; reg < 4; reg++) o[reg] = (__bf16)O[ni][reg];
            *(bf16x4*)&od[ni * 16 + 4 * q] = o;
        }
    }
}

// ---------------------------------------------------------------------------
// Merge split-K halves: y[t][c] = (O_a+O_b)/(l_a+l_b) for t in [1024,2048).
// 512 blocks x 256 threads x 8 elems. Pure elementwise + per-row l lookup.
// ---------------------------------------------------------------------------
__global__ __launch_bounds__(256) void merge_kernel(
    const __bf16* __restrict__ Opart, const float* __restrict__ lpart,
    __bf16* __restrict__ y)
{
    const size_t base = ((size_t)blockIdx.x * 256 + threadIdx.x) * 8;
    const int tr = (int)(base >> 10);         // t - 1024
    const int c = (int)(base & 1023);
    const int h = c >> 6;
    const float inv = 1.0f / (lpart[h * 1024 + tr] +
                              lpart[16 * 1024 + h * 1024 + tr]);
    bf16x8 a = *(const bf16x8*)&Opart[base];
    bf16x8 b = *(const bf16x8*)&Opart[(size_t)1024 * C_EMB + base];
    bf16x8 o;
#pragma unroll
    for (int i = 0; i < 8; i++)
        o[i] = (__bf16)(((float)a[i] + (float)b[i]) * inv);
    *(bf16x8*)&y[(size_t)(1024 + tr) * C_EMB + c] = o;
}

// ---------------------------------------------------------------------------
extern "C" void kernel_launch(void* const* d_in, const int* in_sizes, int n_in,
                              void* d_out, int out_size, void* d_ws, size_t ws_size,
                              hipStream_t stream)
{
    const float* x      = (const float*)d_in[0];
    const float* w_attn = (const float*)d_in[1];
    const float* w_proj = (const float*)d_in[2];
    float* out = (float*)d_out;

    // Workspace: exactly 20 MiB (the r3..r12-proven footprint).
    __bf16* x_bf = (__bf16*)d_ws;                      // 2048x1024  4 MiB
    __bf16* waT  = x_bf + (size_t)T_SEQ * C_EMB;       // 1536x1024  3 MiB
    __bf16* wpT  = waT  + (size_t)C_QKV * C_EMB;       // 1024x1024  2 MiB
    __bf16* qkv  = wpT  + (size_t)C_EMB * C_EMB;       // 2048x1536  6 MiB
    __bf16* Vt   = qkv  + (size_t)T_SEQ * C_QKV;       // 256x2048   1 MiB
    __bf16* y_bf = Vt   + (size_t)256 * T_SEQ;         // 2048x1024  4 MiB
    // Split-K partials REUSE regions dead after GEMM1:
    __bf16* Opart = x_bf;           // 2 x 1024x1024 bf16 = 4 MiB (x_bf region)
    float*  lpart = (float*)waT;    // 2 x 16x1024 fp32 = 128 KB (waT region)

    prep_kernel<<<896, 256, 0, stream>>>(x, w_attn, w_proj, x_bf, waT, wpT);

    // GEMM1 + fused RoPE (+ q softmax/log2e pre-scale) + V-transpose scatter
    gemm_mfma_kernel<true><<<dim3(C_QKV / 64, T_SEQ / 64), 256, 0, stream>>>(
        x_bf, waT, qkv, Vt, nullptr, T_SEQ, C_QKV, C_EMB);

    attn_mfma_kernel<<<dim3(48, N_HEAD), 256, 0, stream>>>(
        qkv, Vt, y_bf, Opart, lpart);

    merge_kernel<<<512, 256, 0, stream>>>(Opart, lpart, y_bf);

    gemm_mfma_kernel<false><<<dim3(C_EMB / 64, T_SEQ / 64), 256, 0, stream>>>(
        y_bf, wpT, nullptr, nullptr, out, T_SEQ, C_EMB, C_EMB);
}